// Round 8
// baseline (146.177 us; speedup 1.0000x reference)
//
#include <hip/hip_runtime.h>

// Harness promotes float16 tensors to float32: x, scales, out are f32;
// weight_packed is int32, one byte (2 nibbles) per element.
#define M 32
#define N 11008
#define K 4096
#define NGROUPS 32
#define BN 64                // n-rows per block (16 per wave)
#define KSPLIT 16            // k-split across blocks
#define KRANGE (K / KSPLIT)  // 256 k per block, single shot (no k-loop)
#define MN (M * N)

typedef _Float16 half8 __attribute__((ext_vector_type(8))); // 4 VGPRs
typedef float floatx4 __attribute__((ext_vector_type(4)));

// LDS rows stored in PAIRS (two 512B rows contiguous = one 1KB gll16 per wave)
// with 16B pad per pair to spread banks across pairs.
#define WPAIR 260 // ints per weight row-pair: 2*128 + 4 pad (1040 B)
#define XPAIR 520 // halves per x row-pair:    2*256 + 8 pad (1040 B)

__device__ inline void gll16(const void* g, void* l) {
    __builtin_amdgcn_global_load_lds(
        (const __attribute__((address_space(1))) unsigned int*)g,
        (__attribute__((address_space(3))) unsigned int*)l, 16, 0, 0);
}

__global__ __launch_bounds__(256) void int4_gemm_kernel(
    const float* __restrict__ x,      // [M][K] f32
    const int* __restrict__ wp,       // [N][K/2] int32, 2 nibbles each
    const float* __restrict__ scales, // [N][NGROUPS] f32
    float* __restrict__ part)         // [KSPLIT][M][N] f32 partials
{
    __shared__ int wsh[32 * WPAIR];      // 64 w-rows: 33.3 KB
    __shared__ _Float16 xs[16 * XPAIR];  // 32 x-rows: 16.6 KB

    const int t    = threadIdx.x;
    const int lane = t & 63;
    const int w    = t >> 6;          // wave id -> n-subtile [w*16, w*16+16)
    const int ks   = blockIdx.x;      // FAST grid dim: k-split index.
    const int n0   = blockIdx.y * BN; // resident cohorts stream rows densely
    const int row  = lane & 15;
    const int quad = lane >> 4;

    const int nw = n0 + w * 16 + row; // this lane's weight row / output col
    const float s0 = scales[nw * NGROUPS + ks * 2];
    const float s1 = scales[nw * NGROUPS + ks * 2 + 1];

    // ---- stage weights: 32 row-pairs x 1KB, 8 gll per wave ----
    #pragma unroll
    for (int i = 0; i < 8; ++i) {
        int p = w * 8 + i;
        int r = 2 * p + (lane >> 5);
        const int* g = wp + (long)(n0 + r) * (K / 2) + ks * (KRANGE / 2) + (lane & 31) * 4;
        gll16(g, &wsh[p * WPAIR]);
    }
    // ---- stage x: load f32 (L2-resident), convert, ds_write f16 ----
    // (replaces the separate xcvt kernel: one fewer launch + graph dep)
    #pragma unroll
    for (int i = 0; i < 4; ++i) {
        int p = w * 4 + i;                 // pair 0..15
        int m = 2 * p + (lane >> 5);
        const float* g = x + m * K + ks * KRANGE + (lane & 31) * 8;
        float4 v0 = *(const float4*)g;
        float4 v1 = *(const float4*)(g + 4);
        half8 h;
        h[0] = (_Float16)v0.x; h[1] = (_Float16)v0.y;
        h[2] = (_Float16)v0.z; h[3] = (_Float16)v0.w;
        h[4] = (_Float16)v1.x; h[5] = (_Float16)v1.y;
        h[6] = (_Float16)v1.z; h[7] = (_Float16)v1.w;
        *(half8*)&xs[p * XPAIR + (lane >> 5) * 256 + (lane & 31) * 8] = h;
    }
    __syncthreads(); // single barrier: drains gll queue + ds_writes once

    const half8 c1032 = (half8)(_Float16)1032.0f; // 0x6408, exact
    floatx4 acc0 = {0.f, 0.f, 0.f, 0.f};
    floatx4 acc1 = {0.f, 0.f, 0.f, 0.f};

    const int wr    = w * 16 + row;                              // local w-row
    const int wbase = (wr >> 1) * WPAIR + (wr & 1) * 128 + quad * 4;
    const int xbase = (row >> 1) * XPAIR + (row & 1) * 256 + quad * 8;

    #pragma unroll
    for (int g = 0; g < 2; ++g) {        // two 128-k scale groups
        floatx4 t0 = {0.f, 0.f, 0.f, 0.f};
        floatx4 t1 = {0.f, 0.f, 0.f, 0.f};
        #pragma unroll
        for (int kk = 0; kk < 4; ++kk) { // 4 MFMA k-steps of 32
            const int kq = g * 4 + kk;
            int4 wv = *(const int4*)&wsh[wbase + kq * 16];
            uint4 uw;
            {
                unsigned int b;
                b = (unsigned int)wv.x; uw.x = ((b | (b << 12)) & 0x000F000Fu) | 0x64006400u;
                b = (unsigned int)wv.y; uw.y = ((b | (b << 12)) & 0x000F000Fu) | 0x64006400u;
                b = (unsigned int)wv.z; uw.z = ((b | (b << 12)) & 0x000F000Fu) | 0x64006400u;
                b = (unsigned int)wv.w; uw.w = ((b | (b << 12)) & 0x000F000Fu) | 0x64006400u;
            }
            half8 bfrag = __builtin_bit_cast(half8, uw) - c1032; // exact (nib-8)
            half8 a0 = *(const half8*)&xs[xbase + kq * 32];
            half8 a1 = *(const half8*)&xs[xbase + 8 * XPAIR + kq * 32]; // m+16
            t0 = __builtin_amdgcn_mfma_f32_16x16x32_f16(a0, bfrag, t0, 0, 0, 0);
            t1 = __builtin_amdgcn_mfma_f32_16x16x32_f16(a1, bfrag, t1, 0, 0, 0);
        }
        const float s = g ? s1 : s0;
        #pragma unroll
        for (int r = 0; r < 4; ++r) {
            acc0[r] += s * t0[r]; // fp32 scale application, matches reference
            acc1[r] += s * t1[r];
        }
    }

    // ---- epilogue: coalesced partial stores (full 64B lines, no atomics) ----
    // C/D layout: col(n) = lane&15, row(m) = quad*4 + r
    float* po = part + (long)ks * MN;
    #pragma unroll
    for (int r = 0; r < 4; ++r) {
        int mr = quad * 4 + r;
        po[mr * N + nw]        = acc0[r];
        po[(mr + 16) * N + nw] = acc1[r];
    }
}

// ---- reduce the 16 k-split partials -> out ----
__global__ __launch_bounds__(256) void reduce_kernel(
    const float* __restrict__ part, float* __restrict__ out)
{
    int o = blockIdx.x * 256 + threadIdx.x; // MN = 352256 = 1376*256
    float s = 0.f;
    #pragma unroll
    for (int j = 0; j < KSPLIT; ++j) s += part[(long)j * MN + o];
    out[o] = s;
}

extern "C" void kernel_launch(void* const* d_in, const int* in_sizes, int n_in,
                              void* d_out, int out_size, void* d_ws, size_t ws_size,
                              hipStream_t stream) {
    const float* x      = (const float*)d_in[0];
    const int* wp       = (const int*)d_in[1];
    const float* scales = (const float*)d_in[2];
    float* out          = (float*)d_out;
    float* part         = (float*)d_ws; // KSPLIT*M*N f32 = 22.5 MB

    int4_gemm_kernel<<<dim3(KSPLIT, N / BN), 256, 0, stream>>>(x, wp, scales, part);
    reduce_kernel<<<dim3(MN / 256), 256, 0, stream>>>(part, out);
}